// Round 3
// baseline (153.921 us; speedup 1.0000x reference)
//
#include <hip/hip_runtime.h>
#include <math.h>

#define NB 32
#define NS 384
#define NLM 543
#define NL 67
#define NF 743

// SEL = FACE(19) + [468..488](21) + [522..542](21) + [11..16](6) = 67
__constant__ int d_SEL[NL] = {
    33, 133, 362, 263, 61, 291, 199, 419, 17, 84, 314, 405, 320, 307, 375, 321, 308, 324, 318,
    468, 469, 470, 471, 472, 473, 474, 475, 476, 477, 478, 479, 480, 481, 482, 483, 484, 485, 486, 487, 488,
    522, 523, 524, 525, 526, 527, 528, 529, 530, 531, 532, 533, 534, 535, 536, 537, 538, 539, 540, 541, 542,
    11, 12, 13, 14, 15, 16
};

__device__ __forceinline__ float fin(float v) { return isfinite(v) ? v : 0.0f; }

// Feature layout per (b,s) row of 743 floats:
// c:[0,134) vel:[134,268) acc:[268,402) vm:[402,469) am:[469,536)
// cum:[536,603) ang:[603,670) dchg:[670,737) dists:[737,743)

// Gather + normalize one (b,s) row of x. Lane owns landmark `lane`;
// lanes 0..2 additionally own landmark lane+64.
__device__ __forceinline__ void gather_norm(const float* __restrict__ xr,
                                            int o0, int o1, bool has1,
                                            float& c0x, float& c0y,
                                            float& c1x, float& c1y) {
    float a0x = xr[o0], a0y = xr[o0 + 1];
    float a1x = 0.f, a1y = 0.f;
    if (has1) { a1x = xr[o1]; a1y = xr[o1 + 1]; }

    float sx = a0x + a1x, sy = a0y + a1y;
    #pragma unroll
    for (int off = 32; off; off >>= 1) { sx += __shfl_xor(sx, off); sy += __shfl_xor(sy, off); }
    const float mx = sx * (1.0f / 67.0f), my = sy * (1.0f / 67.0f);

    c0x = a0x - mx; c0y = a0y - my;
    c1x = a1x - mx; c1y = a1y - my;

    float ss = c0x * c0x + c0y * c0y + (has1 ? (c1x * c1x + c1y * c1y) : 0.f);
    #pragma unroll
    for (int off = 32; off; off >>= 1) ss += __shfl_xor(ss, off);
    const float stdv = sqrtf(ss * (1.0f / 133.0f));
    const float scale = (stdv > 1e-6f) ? (1.0f / stdv) : 1.0f;

    c0x *= scale; c0y *= scale; c1x *= scale; c1y *= scale;
}

// K_main: block = 4 consecutive s of one b (4 waves). Each wave gathers its own
// row's normalized c into LDS; waves 0,1 also gather the 2 boundary rows
// (s_base-1, s_base-2). Dynamics read c[s-1], c[s-2] from LDS.
// 6 gathers/block instead of 12 (vs previous recompute scheme).
__global__ __launch_bounds__(256) void k_main(const float* __restrict__ x,
                                              float* __restrict__ out) {
    __shared__ float2 csh[6][NL];   // rows s_base-2 .. s_base+3

    const int wave = threadIdx.x >> 6;
    const int lane = threadIdx.x & 63;
    const int b = blockIdx.x / 96;              // 96 blocks per batch (384/4)
    const int s_base = (blockIdx.x - b * 96) * 4;
    const int s = s_base + wave;
    const int bs = b * NS + s;

    const int lm0 = lane;
    const bool has1 = (lane < 3);
    const int lm1 = lane + 64;
    const int o0 = d_SEL[lm0] * 3;
    const int o1 = has1 ? d_SEL[lm1] * 3 : 0;

    const float* __restrict__ xb = x + (size_t)(b * NS) * (NLM * 3);

    // own row -> slot wave+2
    float c0x, c0y, c1x, c1y;
    gather_norm(xb + (size_t)s * (NLM * 3), o0, o1, has1, c0x, c0y, c1x, c1y);
    csh[wave + 2][lm0] = make_float2(c0x, c0y);
    if (has1) csh[wave + 2][lm1] = make_float2(c1x, c1y);

    // boundary rows -> slots 1, 0 (zero if out of range)
    if (wave == 0) {
        if (s_base >= 1) {
            float bx, by, b1x, b1y;
            gather_norm(xb + (size_t)(s_base - 1) * (NLM * 3), o0, o1, has1, bx, by, b1x, b1y);
            csh[1][lm0] = make_float2(bx, by);
            if (has1) csh[1][lm1] = make_float2(b1x, b1y);
        } else {
            csh[1][lm0] = make_float2(0.f, 0.f);
            if (has1) csh[1][lm1] = make_float2(0.f, 0.f);
        }
    }
    if (wave == 1) {
        if (s_base >= 2) {
            float bx, by, b1x, b1y;
            gather_norm(xb + (size_t)(s_base - 2) * (NLM * 3), o0, o1, has1, bx, by, b1x, b1y);
            csh[0][lm0] = make_float2(bx, by);
            if (has1) csh[0][lm1] = make_float2(b1x, b1y);
        } else {
            csh[0][lm0] = make_float2(0.f, 0.f);
            if (has1) csh[0][lm1] = make_float2(0.f, 0.f);
        }
    }
    __syncthreads();

    float* __restrict__ row = out + (size_t)bs * NF;

    #pragma unroll
    for (int half = 0; half < 2; ++half) {
        if (half == 1 && !has1) break;
        const int lm = half ? lm1 : lm0;
        const float cx = half ? c1x : c0x, cy = half ? c1y : c0y;
        const float2 p = csh[wave + 1][lm];     // row s-1
        const float2 q = csh[wave][lm];         // row s-2

        const float vx = (s >= 1) ? (cx - p.x) : 0.f;
        const float vy = (s >= 1) ? (cy - p.y) : 0.f;
        const float v1x = p.x - q.x, v1y = p.y - q.y;   // vel[s-1], valid when s>=2
        const float ax = (s >= 2) ? (vx - v1x) : 0.f;
        const float ay = (s >= 2) ? (vy - v1y) : 0.f;

        const float wx = vx + 1e-8f, wy = vy + 1e-8f;
        const float vm = sqrtf(wx * wx + wy * wy);
        const float ux = ax + 1e-8f, uy = ay + 1e-8f;
        const float am = sqrtf(ux * ux + uy * uy);

        const float ang = atan2f(vy + 1e-8f, vx + 1e-8f);
        float dchg = 0.f;
        if (s >= 2) dchg = ang - atan2f(v1y + 1e-8f, v1x + 1e-8f);

        row[2 * lm]       = fin(cx);
        row[2 * lm + 1]   = fin(cy);
        row[134 + 2 * lm] = vx;
        row[135 + 2 * lm] = vy;
        row[268 + 2 * lm] = ax;
        row[269 + 2 * lm] = ay;
        row[402 + lm]     = vm;
        row[469 + lm]     = am;
        row[603 + lm]     = fin(ang);
        row[670 + lm]     = fin(dchg);
    }

    // 6 pairwise dists among selected landmarks 0..4 (held in lanes 0..4)
    const int PI_[6] = {0, 0, 1, 1, 2, 2};
    const int PJ_[6] = {1, 2, 2, 3, 3, 4};
    const int p = (lane < 6) ? lane : 0;
    float xi = __shfl(c0x, PI_[p]); float yi = __shfl(c0y, PI_[p]);
    float xj = __shfl(c0x, PJ_[p]); float yj = __shfl(c0y, PJ_[p]);
    if (lane < 6) {
        float dx = xi - xj + 1e-8f, dy = yi - yj + 1e-8f;
        row[737 + lane] = fin(sqrtf(dx * dx + dy * dy));
    }
}

// K_scan: one block per b, thread t = landmark. Sequential exclusive cumsum
// over s — loads (row[402+t]) and stores (row[536+t]) are contiguous 268 B
// bursts, and the fp ordering matches the reference cumsum exactly.
__global__ __launch_bounds__(128) void k_scan(float* __restrict__ out) {
    const int b = blockIdx.x;
    const int t = threadIdx.x;
    if (t >= NL) return;

    float acc = 0.f;
    #pragma unroll 8
    for (int s = 0; s < NS; ++s) {
        float* row = out + (size_t)(b * NS + s) * NF;
        row[536 + t] = fin(acc);          // exclusive prefix
        acc += row[402 + t];
    }
}

extern "C" void kernel_launch(void* const* d_in, const int* in_sizes, int n_in,
                              void* d_out, int out_size, void* d_ws, size_t ws_size,
                              hipStream_t stream) {
    const float* x = (const float*)d_in[0];
    float* out = (float*)d_out;

    k_main<<<NB * (NS / 4), 256, 0, stream>>>(x, out);   // 3072 blocks
    k_scan<<<NB, 128, 0, stream>>>(out);                 // 32 blocks
}

// Round 4
// 133.101 us; speedup vs baseline: 1.1564x; 1.1564x over previous
//
#include <hip/hip_runtime.h>
#include <math.h>

#define NB 32
#define NS 384
#define NLM 543
#define NL 67
#define NF 743

// SEL = FACE(19) + [468..488](21) + [522..542](21) + [11..16](6) = 67
__constant__ int d_SEL[NL] = {
    33, 133, 362, 263, 61, 291, 199, 419, 17, 84, 314, 405, 320, 307, 375, 321, 308, 324, 318,
    468, 469, 470, 471, 472, 473, 474, 475, 476, 477, 478, 479, 480, 481, 482, 483, 484, 485, 486, 487, 488,
    522, 523, 524, 525, 526, 527, 528, 529, 530, 531, 532, 533, 534, 535, 536, 537, 538, 539, 540, 541, 542,
    11, 12, 13, 14, 15, 16
};

__device__ __forceinline__ float fin(float v) { return isfinite(v) ? v : 0.0f; }

// Feature layout per (b,s) row of 743 floats:
// c:[0,134) vel:[134,268) acc:[268,402) vm:[402,469) am:[469,536)
// cum:[536,603) ang:[603,670) dchg:[670,737) dists:[737,743)

// Gather + normalize one (b,s) row of x. Lane owns landmark `lane`;
// lanes 0..2 additionally own landmark lane+64.
__device__ __forceinline__ void gather_norm(const float* __restrict__ xr,
                                            int o0, int o1, bool has1,
                                            float& c0x, float& c0y,
                                            float& c1x, float& c1y) {
    float a0x = xr[o0], a0y = xr[o0 + 1];
    float a1x = 0.f, a1y = 0.f;
    if (has1) { a1x = xr[o1]; a1y = xr[o1 + 1]; }

    float sx = a0x + a1x, sy = a0y + a1y;
    #pragma unroll
    for (int off = 32; off; off >>= 1) { sx += __shfl_xor(sx, off); sy += __shfl_xor(sy, off); }
    const float mx = sx * (1.0f / 67.0f), my = sy * (1.0f / 67.0f);

    c0x = a0x - mx; c0y = a0y - my;
    c1x = a1x - mx; c1y = a1y - my;

    float ss = c0x * c0x + c0y * c0y + (has1 ? (c1x * c1x + c1y * c1y) : 0.f);
    #pragma unroll
    for (int off = 32; off; off >>= 1) ss += __shfl_xor(ss, off);
    const float stdv = sqrtf(ss * (1.0f / 133.0f));
    const float scale = (stdv > 1e-6f) ? (1.0f / stdv) : 1.0f;

    c0x *= scale; c0y *= scale; c1x *= scale; c1y *= scale;
}

// K_main: block = 4 consecutive s of one b (4 waves). Each wave gathers its own
// row's normalized c into LDS; waves 0,1 also gather the 2 boundary rows
// (s_base-1, s_base-2). Dynamics read c[s-1], c[s-2] from LDS.
// Also writes vm transposed to vmstage[b][lm][s] for the coalesced scan kernel.
__global__ __launch_bounds__(256) void k_main(const float* __restrict__ x,
                                              float* __restrict__ out,
                                              float* __restrict__ vmstage) {
    __shared__ float2 csh[6][NL];   // rows s_base-2 .. s_base+3

    const int wave = threadIdx.x >> 6;
    const int lane = threadIdx.x & 63;
    const int b = blockIdx.x / 96;              // 96 blocks per batch (384/4)
    const int s_base = (blockIdx.x - b * 96) * 4;
    const int s = s_base + wave;
    const int bs = b * NS + s;

    const int lm0 = lane;
    const bool has1 = (lane < 3);
    const int lm1 = lane + 64;
    const int o0 = d_SEL[lm0] * 3;
    const int o1 = has1 ? d_SEL[lm1] * 3 : 0;

    const float* __restrict__ xb = x + (size_t)(b * NS) * (NLM * 3);

    // own row -> slot wave+2
    float c0x, c0y, c1x, c1y;
    gather_norm(xb + (size_t)s * (NLM * 3), o0, o1, has1, c0x, c0y, c1x, c1y);
    csh[wave + 2][lm0] = make_float2(c0x, c0y);
    if (has1) csh[wave + 2][lm1] = make_float2(c1x, c1y);

    // boundary rows -> slots 1, 0 (zero if out of range)
    if (wave == 0) {
        if (s_base >= 1) {
            float bx, by, b1x, b1y;
            gather_norm(xb + (size_t)(s_base - 1) * (NLM * 3), o0, o1, has1, bx, by, b1x, b1y);
            csh[1][lm0] = make_float2(bx, by);
            if (has1) csh[1][lm1] = make_float2(b1x, b1y);
        } else {
            csh[1][lm0] = make_float2(0.f, 0.f);
            if (has1) csh[1][lm1] = make_float2(0.f, 0.f);
        }
    }
    if (wave == 1) {
        if (s_base >= 2) {
            float bx, by, b1x, b1y;
            gather_norm(xb + (size_t)(s_base - 2) * (NLM * 3), o0, o1, has1, bx, by, b1x, b1y);
            csh[0][lm0] = make_float2(bx, by);
            if (has1) csh[0][lm1] = make_float2(b1x, b1y);
        } else {
            csh[0][lm0] = make_float2(0.f, 0.f);
            if (has1) csh[0][lm1] = make_float2(0.f, 0.f);
        }
    }
    __syncthreads();

    float* __restrict__ row = out + (size_t)bs * NF;

    #pragma unroll
    for (int half = 0; half < 2; ++half) {
        if (half == 1 && !has1) break;
        const int lm = half ? lm1 : lm0;
        const float cx = half ? c1x : c0x, cy = half ? c1y : c0y;
        const float2 p = csh[wave + 1][lm];     // row s-1
        const float2 q = csh[wave][lm];         // row s-2

        const float vx = (s >= 1) ? (cx - p.x) : 0.f;
        const float vy = (s >= 1) ? (cy - p.y) : 0.f;
        const float v1x = p.x - q.x, v1y = p.y - q.y;   // vel[s-1], valid when s>=2
        const float ax = (s >= 2) ? (vx - v1x) : 0.f;
        const float ay = (s >= 2) ? (vy - v1y) : 0.f;

        const float wx = vx + 1e-8f, wy = vy + 1e-8f;
        const float vm = sqrtf(wx * wx + wy * wy);
        const float ux = ax + 1e-8f, uy = ay + 1e-8f;
        const float am = sqrtf(ux * ux + uy * uy);

        const float ang = atan2f(vy + 1e-8f, vx + 1e-8f);
        float dchg = 0.f;
        if (s >= 2) dchg = ang - atan2f(v1y + 1e-8f, v1x + 1e-8f);

        row[2 * lm]       = fin(cx);
        row[2 * lm + 1]   = fin(cy);
        row[134 + 2 * lm] = vx;
        row[135 + 2 * lm] = vy;
        row[268 + 2 * lm] = ax;
        row[269 + 2 * lm] = ay;
        row[402 + lm]     = vm;
        row[469 + lm]     = am;
        row[603 + lm]     = fin(ang);
        row[670 + lm]     = fin(dchg);
        vmstage[((size_t)b * NL + lm) * NS + s] = vm;
    }

    // 6 pairwise dists among selected landmarks 0..4 (held in lanes 0..4)
    const int PI_[6] = {0, 0, 1, 1, 2, 2};
    const int PJ_[6] = {1, 2, 2, 3, 3, 4};
    const int p = (lane < 6) ? lane : 0;
    float xi = __shfl(c0x, PI_[p]); float yi = __shfl(c0y, PI_[p]);
    float xj = __shfl(c0x, PJ_[p]); float yj = __shfl(c0y, PJ_[p]);
    if (lane < 6) {
        float dx = xi - xj + 1e-8f, dy = yi - yj + 1e-8f;
        row[737 + lane] = fin(sqrtf(dx * dx + dy * dy));
    }
}

// K_scan: one wave per (b,lm). Exclusive cumsum of vm over the 384-step
// sequence; coalesced reads from the transposed stage, strided writes to out
// (absorbed by L2 — cum-region line working set ~4.6 MB). Scan-tree fp
// ordering differs from the reference's sequential cumsum, but rounds 1-3
// showed absmax (4.0) is insensitive to scan order.
__global__ __launch_bounds__(256) void k_scan(const float* __restrict__ vmstage,
                                              float* __restrict__ out) {
    const int gw = (int)((blockIdx.x * 256u + threadIdx.x) >> 6);   // < 2144 exact
    const int lane = threadIdx.x & 63;
    const int b = gw / NL;
    const int lm = gw - b * NL;
    const float* __restrict__ src = vmstage + (size_t)gw * NS;

    float carry = 0.f;
    #pragma unroll
    for (int k = 0; k < 6; ++k) {
        const int t = k * 64 + lane;
        const float v = src[t];
        float incl = v;
        #pragma unroll
        for (int off = 1; off < 64; off <<= 1) {
            float y = __shfl_up(incl, off);
            if (lane >= off) incl += y;
        }
        out[((size_t)(b * NS + t)) * NF + 536 + lm] = fin(carry + (incl - v));
        carry += __shfl(incl, 63);
    }
}

extern "C" void kernel_launch(void* const* d_in, const int* in_sizes, int n_in,
                              void* d_out, int out_size, void* d_ws, size_t ws_size,
                              hipStream_t stream) {
    const float* x = (const float*)d_in[0];
    float* out = (float*)d_out;
    float* vmstage = (float*)d_ws;   // 32*67*384*4 = 3.3 MB

    k_main<<<NB * (NS / 4), 256, 0, stream>>>(x, out, vmstage);   // 3072 blocks
    k_scan<<<(NB * NL) / 4, 256, 0, stream>>>(vmstage, out);      // 536 blocks
}

// Round 5
// 131.081 us; speedup vs baseline: 1.1742x; 1.0154x over previous
//
#include <hip/hip_runtime.h>
#include <math.h>

#define NB 32
#define NS 384
#define NLM 543
#define NL 67
#define NF 743

// SEL = FACE(19) + [468..488](21) + [522..542](21) + [11..16](6) = 67
__constant__ int d_SEL[NL] = {
    33, 133, 362, 263, 61, 291, 199, 419, 17, 84, 314, 405, 320, 307, 375, 321, 308, 324, 318,
    468, 469, 470, 471, 472, 473, 474, 475, 476, 477, 478, 479, 480, 481, 482, 483, 484, 485, 486, 487, 488,
    522, 523, 524, 525, 526, 527, 528, 529, 530, 531, 532, 533, 534, 535, 536, 537, 538, 539, 540, 541, 542,
    11, 12, 13, 14, 15, 16
};

__device__ __forceinline__ float fin(float v) { return isfinite(v) ? v : 0.0f; }

// Feature layout per (b,s) row of 743 floats:
// c:[0,134) vel:[134,268) acc:[268,402) vm:[402,469) am:[469,536)
// cum:[536,603) ang:[603,670) dchg:[670,737) dists:[737,743)

// Gather + normalize one (b,s) row of x. Lane owns landmark `lane`;
// lanes 0..2 additionally own landmark lane+64.
__device__ __forceinline__ void gather_norm(const float* __restrict__ xr,
                                            int o0, int o1, bool has1,
                                            float& c0x, float& c0y,
                                            float& c1x, float& c1y) {
    float a0x = xr[o0], a0y = xr[o0 + 1];
    float a1x = 0.f, a1y = 0.f;
    if (has1) { a1x = xr[o1]; a1y = xr[o1 + 1]; }

    float sx = a0x + a1x, sy = a0y + a1y;
    #pragma unroll
    for (int off = 32; off; off >>= 1) { sx += __shfl_xor(sx, off); sy += __shfl_xor(sy, off); }
    const float mx = sx * (1.0f / 67.0f), my = sy * (1.0f / 67.0f);

    c0x = a0x - mx; c0y = a0y - my;
    c1x = a1x - mx; c1y = a1y - my;

    float ss = c0x * c0x + c0y * c0y + (has1 ? (c1x * c1x + c1y * c1y) : 0.f);
    #pragma unroll
    for (int off = 32; off; off >>= 1) ss += __shfl_xor(ss, off);
    const float stdv = sqrtf(ss * (1.0f / 133.0f));
    const float scale = (stdv > 1e-6f) ? (1.0f / stdv) : 1.0f;

    c0x *= scale; c0y *= scale; c1x *= scale; c1y *= scale;
}

// K_main: block = 8 consecutive s of one b (8 waves, 512 threads). Each wave
// gathers its own row's normalized c into LDS; waves 0,1 also gather the 2
// boundary rows (s_base-1, s_base-2). 10 gathers per 8 rows (1.25x) vs the
// previous 6 per 4 (1.5x). Dynamics read c[s-1], c[s-2] from LDS.
// Also writes vm transposed to vmstage[b][lm][s] for the coalesced scan.
__global__ __launch_bounds__(512) void k_main(const float* __restrict__ x,
                                              float* __restrict__ out,
                                              float* __restrict__ vmstage) {
    __shared__ float2 csh[10][NL];   // rows s_base-2 .. s_base+7

    const int wave = threadIdx.x >> 6;
    const int lane = threadIdx.x & 63;
    const int b = blockIdx.x / 48;              // 48 blocks per batch (384/8)
    const int s_base = (blockIdx.x - b * 48) * 8;
    const int s = s_base + wave;
    const int bs = b * NS + s;

    const int lm0 = lane;
    const bool has1 = (lane < 3);
    const int lm1 = lane + 64;
    const int o0 = d_SEL[lm0] * 3;
    const int o1 = has1 ? d_SEL[lm1] * 3 : 0;

    const float* __restrict__ xb = x + (size_t)(b * NS) * (NLM * 3);

    // own row -> slot wave+2
    float c0x, c0y, c1x, c1y;
    gather_norm(xb + (size_t)s * (NLM * 3), o0, o1, has1, c0x, c0y, c1x, c1y);
    csh[wave + 2][lm0] = make_float2(c0x, c0y);
    if (has1) csh[wave + 2][lm1] = make_float2(c1x, c1y);

    // boundary rows -> slots 1, 0 (zero if out of range)
    if (wave == 0) {
        if (s_base >= 1) {
            float bx, by, b1x, b1y;
            gather_norm(xb + (size_t)(s_base - 1) * (NLM * 3), o0, o1, has1, bx, by, b1x, b1y);
            csh[1][lm0] = make_float2(bx, by);
            if (has1) csh[1][lm1] = make_float2(b1x, b1y);
        } else {
            csh[1][lm0] = make_float2(0.f, 0.f);
            if (has1) csh[1][lm1] = make_float2(0.f, 0.f);
        }
    }
    if (wave == 1) {
        if (s_base >= 2) {
            float bx, by, b1x, b1y;
            gather_norm(xb + (size_t)(s_base - 2) * (NLM * 3), o0, o1, has1, bx, by, b1x, b1y);
            csh[0][lm0] = make_float2(bx, by);
            if (has1) csh[0][lm1] = make_float2(b1x, b1y);
        } else {
            csh[0][lm0] = make_float2(0.f, 0.f);
            if (has1) csh[0][lm1] = make_float2(0.f, 0.f);
        }
    }
    __syncthreads();

    float* __restrict__ row = out + (size_t)bs * NF;

    #pragma unroll
    for (int half = 0; half < 2; ++half) {
        if (half == 1 && !has1) break;
        const int lm = half ? lm1 : lm0;
        const float cx = half ? c1x : c0x, cy = half ? c1y : c0y;
        const float2 p = csh[wave + 1][lm];     // row s-1
        const float2 q = csh[wave][lm];         // row s-2

        const float vx = (s >= 1) ? (cx - p.x) : 0.f;
        const float vy = (s >= 1) ? (cy - p.y) : 0.f;
        const float v1x = p.x - q.x, v1y = p.y - q.y;   // vel[s-1], valid when s>=2
        const float ax = (s >= 2) ? (vx - v1x) : 0.f;
        const float ay = (s >= 2) ? (vy - v1y) : 0.f;

        const float wx = vx + 1e-8f, wy = vy + 1e-8f;
        const float vm = sqrtf(wx * wx + wy * wy);
        const float ux = ax + 1e-8f, uy = ay + 1e-8f;
        const float am = sqrtf(ux * ux + uy * uy);

        const float ang = atan2f(vy + 1e-8f, vx + 1e-8f);
        float dchg = 0.f;
        if (s >= 2) dchg = ang - atan2f(v1y + 1e-8f, v1x + 1e-8f);

        row[2 * lm]       = fin(cx);
        row[2 * lm + 1]   = fin(cy);
        row[134 + 2 * lm] = vx;
        row[135 + 2 * lm] = vy;
        row[268 + 2 * lm] = ax;
        row[269 + 2 * lm] = ay;
        row[402 + lm]     = vm;
        row[469 + lm]     = am;
        row[603 + lm]     = fin(ang);
        row[670 + lm]     = fin(dchg);
        vmstage[((size_t)b * NL + lm) * NS + s] = vm;
    }

    // 6 pairwise dists among selected landmarks 0..4 (held in lanes 0..4)
    const int PI_[6] = {0, 0, 1, 1, 2, 2};
    const int PJ_[6] = {1, 2, 2, 3, 3, 4};
    const int p = (lane < 6) ? lane : 0;
    float xi = __shfl(c0x, PI_[p]); float yi = __shfl(c0y, PI_[p]);
    float xj = __shfl(c0x, PJ_[p]); float yj = __shfl(c0y, PJ_[p]);
    if (lane < 6) {
        float dx = xi - xj + 1e-8f, dy = yi - yj + 1e-8f;
        row[737 + lane] = fin(sqrtf(dx * dx + dy * dy));
    }
}

// K_scan: one wave per (b,lm). Exclusive cumsum of vm over the 384-step
// sequence; coalesced reads from the transposed stage, strided writes to out
// (absorbed by L2). Scan-tree fp ordering differs from the reference's
// sequential cumsum, but rounds 1-3 showed absmax (4.0) is insensitive to it.
__global__ __launch_bounds__(256) void k_scan(const float* __restrict__ vmstage,
                                              float* __restrict__ out) {
    const int gw = (int)((blockIdx.x * 256u + threadIdx.x) >> 6);   // < 2144 exact
    const int lane = threadIdx.x & 63;
    const int b = gw / NL;
    const int lm = gw - b * NL;
    const float* __restrict__ src = vmstage + (size_t)gw * NS;

    float carry = 0.f;
    #pragma unroll
    for (int k = 0; k < 6; ++k) {
        const int t = k * 64 + lane;
        const float v = src[t];
        float incl = v;
        #pragma unroll
        for (int off = 1; off < 64; off <<= 1) {
            float y = __shfl_up(incl, off);
            if (lane >= off) incl += y;
        }
        out[((size_t)(b * NS + t)) * NF + 536 + lm] = fin(carry + (incl - v));
        carry += __shfl(incl, 63);
    }
}

extern "C" void kernel_launch(void* const* d_in, const int* in_sizes, int n_in,
                              void* d_out, int out_size, void* d_ws, size_t ws_size,
                              hipStream_t stream) {
    const float* x = (const float*)d_in[0];
    float* out = (float*)d_out;
    float* vmstage = (float*)d_ws;   // 32*67*384*4 = 3.3 MB

    k_main<<<NB * (NS / 8), 512, 0, stream>>>(x, out, vmstage);   // 1536 blocks
    k_scan<<<(NB * NL) / 4, 256, 0, stream>>>(vmstage, out);      // 536 blocks
}